// Round 5
// baseline (75.913 us; speedup 1.0000x reference)
//
#include <hip/hip_runtime.h>
#include <hip/hip_bf16.h>

// Splat2D: out[n,c,h,w] = sum_p exp(-((h-y)^2+(w-x)^2) * 0.5/sigma_n^2) * v[n,p,c]
// R5: cut LDS-pipe issue count 4x (DS was the bottleneck, not VALU).
//   Block = 1024 thr = 16 waves; wave w = point-segment w (64 points);
//   lane L handles pixels L and L+64 of one image row (h = blockIdx%H).
//   Inner loop: ONE broadcast ds_read_b128 {x, rv0, rv1, rv2} per point,
//   serving 2 pixels. Row factor exp2(s*(h-y)^2) folded into rv* at stage.
//   Weight = exp2(-(u^2)), u = (fx - x)*r, r = sqrt(log2e/2)/sigma  (exact
//   quadratic -> no cancellation).
//   Tail: per-wave partials -> LDS -> 6 waves reduce 16 segs, direct stores.

#define MAINBLOCK 1024
#define NWAVE 16

__device__ __forceinline__ float fast_exp2(float x) {
#if __has_builtin(__builtin_amdgcn_exp2f)
    return __builtin_amdgcn_exp2f(x);
#else
    return exp2f(x);
#endif
}

__global__ __launch_bounds__(MAINBLOCK) void splat2d_row2(
    const float* __restrict__ coords,   // [N, P, 2] (x, y)
    const float* __restrict__ vals,     // [N, P, 3]
    const float* __restrict__ sigma,    // [N, 1]
    float*       __restrict__ out,      // [N, 3, H, W]
    int P, int H, int W)                // W == 128, P <= 1024, P%16 == 0
{
    __shared__ float4 ptA[1024];            // {x, rv0, rv1, rv2}
    __shared__ float  red[NWAVE * 384];     // [wave][j<6][lane]

    const int n = blockIdx.x / H;
    const int h = blockIdx.x % H;
    const int tid  = threadIdx.x;
    const int lane = tid & 63;
    const int wv   = tid >> 6;              // 0..15, = point segment

    const float sg = sigma[n];
    const float s2 = 0.721347520444482f / (sg * sg);   // log2(e)/2 / sigma^2
    const float r  = sqrtf(s2);
    const float fh = (float)h;

    const float* __restrict__ cp = coords + (size_t)n * P * 2;
    const float* __restrict__ vp = vals   + (size_t)n * P * 3;

    // ---- stage all P points; fold row factor into values ----
    for (int p = tid; p < P; p += MAINBLOCK) {
        const float x  = cp[2 * p + 0];
        const float y  = cp[2 * p + 1];
        const float v0 = vp[3 * p + 0];
        const float v1 = vp[3 * p + 1];
        const float v2 = vp[3 * p + 2];
        const float uy = (fh - y) * r;
        const float rh = fast_exp2(-(uy * uy));     // row factor
        ptA[p] = make_float4(x, rh * v0, rh * v1, rh * v2);
    }
    __syncthreads();

    // ---- inner loop: lane's two pixels vs this wave's point segment ----
    const float fx0 = (float)lane;          // pixel L
    const float r64 = 64.0f * r;            // u1 = u0 + 64*r

    const int PS = P / NWAVE;
    const int p0 = wv * PS;

    float a0 = 0.f, a1 = 0.f, a2 = 0.f;     // pixel L
    float b0 = 0.f, b1 = 0.f, b2 = 0.f;     // pixel L+64

#pragma unroll 8
    for (int i = 0; i < PS; ++i) {
        const float4 q = ptA[p0 + i];       // broadcast ds_read_b128
        const float u0 = (fx0 - q.x) * r;   // sub, mul
        const float u1 = u0 + r64;          // add
        const float w0 = fast_exp2(-(u0 * u0));   // mul, v_exp_f32(-mod)
        const float w1 = fast_exp2(-(u1 * u1));   // mul, v_exp_f32(-mod)
        a0 = fmaf(w0, q.y, a0);
        a1 = fmaf(w0, q.z, a1);
        a2 = fmaf(w0, q.w, a2);
        b0 = fmaf(w1, q.y, b0);
        b1 = fmaf(w1, q.z, b1);
        b2 = fmaf(w1, q.w, b2);
    }

    // ---- per-wave partials -> LDS ----
    float* rw = red + wv * 384;
    rw[0 * 64 + lane] = a0;
    rw[1 * 64 + lane] = a1;
    rw[2 * 64 + lane] = a2;
    rw[3 * 64 + lane] = b0;
    rw[4 * 64 + lane] = b1;
    rw[5 * 64 + lane] = b2;
    __syncthreads();

    // ---- 6 waves reduce the 16 segments, store coalesced ----
    if (tid < 384) {
        float acc = 0.f;
#pragma unroll
        for (int w = 0; w < NWAVE; ++w)
            acc += red[w * 384 + tid];      // lane-consecutive: conflict-free
        const int j  = tid >> 6;            // 0..5
        const int L  = tid & 63;
        const int c  = j % 3;
        const int px = (j / 3) * 64 + L;
        const size_t hw = (size_t)H * W;
        out[((size_t)n * 3 + c) * hw + (size_t)h * W + px] = acc;
    }
}

// ---------- generic fallback (R3 structure) ----------
#define BLOCK 256
#define SEGS  8

__global__ __launch_bounds__(BLOCK) void splat2d_lds(
    const float* __restrict__ coords, const float* __restrict__ vals,
    const float* __restrict__ sigma, const int* __restrict__ wptr,
    float* __restrict__ out, int P, int pixPerN, int blocksPerN, int nSeg)
{
    const int PS_MAX = 1024;
    __shared__ float4 ptA[PS_MAX / SEGS];
    __shared__ float2 ptB[PS_MAX / SEGS];

    const int W = *wptr;
    int t = blockIdx.x;
    const int seg = t % nSeg;  t /= nSeg;
    const int n   = t / blocksPerN;
    const int blk = t % blocksPerN;

    const float sg = sigma[n];
    const float s  = -1.44269504088896f * 0.5f / (sg * sg);

    const int PS = P / nSeg;
    const int p0 = seg * PS;
    const float* __restrict__ cp = coords + ((size_t)n * P + p0) * 2;
    const float* __restrict__ vp = vals   + ((size_t)n * P + p0) * 3;

    for (int p = threadIdx.x; p < PS; p += BLOCK) {
        const float x  = cp[2 * p + 0];
        const float y  = cp[2 * p + 1];
        const float c  = s * fmaf(x, x, y * y);
        ptA[p] = make_float4(x, y, c, vp[3 * p + 0]);
        ptB[p] = make_float2(vp[3 * p + 1], vp[3 * p + 2]);
    }
    __syncthreads();

    const int pix = blk * BLOCK + threadIdx.x;
    const int h = pix / W;
    const int w = pix - h * W;
    const float fx = (float)w, fy = (float)h;
    const float tx = -2.0f * s * fx, ty = -2.0f * s * fy;
    const float bb = s * fmaf(fx, fx, fy * fy);

    float a0 = 0.f, a1 = 0.f, a2 = 0.f;
#pragma unroll 8
    for (int p = 0; p < PS; ++p) {
        const float4 q = ptA[p];
        const float2 rr = ptB[p];
        const float e = fmaf(tx, q.x, fmaf(ty, q.y, bb + q.z));
        const float wgt = fast_exp2(e);
        a0 = fmaf(wgt, q.w, a0);
        a1 = fmaf(wgt, rr.x, a1);
        a2 = fmaf(wgt, rr.y, a2);
    }

    const size_t base = ((size_t)n * 3) * (size_t)pixPerN + (size_t)pix;
    unsafeAtomicAdd(&out[base],                       a0);
    unsafeAtomicAdd(&out[base + (size_t)pixPerN],     a1);
    unsafeAtomicAdd(&out[base + 2 * (size_t)pixPerN], a2);
}

extern "C" void kernel_launch(void* const* d_in, const int* in_sizes, int n_in,
                              void* d_out, int out_size, void* d_ws, size_t ws_size,
                              hipStream_t stream) {
    const float* coords = (const float*)d_in[0];   // [N,P,2]
    const float* vals   = (const float*)d_in[1];   // [N,P,3]
    const float* sigma  = (const float*)d_in[2];   // [N,1]
    const int* wptr = (const int*)d_in[4];         // width (device scalar)

    const int N = in_sizes[2];                 // sigma has N elements
    const int P = in_sizes[0] / (2 * N);       // coords = N*P*2
    const int C = in_sizes[1] / (N * P);       // values = N*P*C  (C==3)
    const int pixPerN = out_size / (N * C);    // H*W

    float* out = (float*)d_out;

    if (pixPerN == 16384 && P <= 1024 && (P % NWAVE) == 0 && C == 3) {
        const int H = 128, W = 128;
        const int grid = N * H;   // 512 blocks of 1024 threads
        splat2d_row2<<<grid, MAINBLOCK, 0, stream>>>(coords, vals, sigma,
                                                     out, P, H, W);
    } else {
        const int nSeg = (P % SEGS == 0 && P <= 1024) ? SEGS : 1;
        const int blocksPerN = pixPerN / BLOCK;
        const int grid = N * blocksPerN * nSeg;
        hipMemsetAsync(out, 0, (size_t)out_size * sizeof(float), stream);
        splat2d_lds<<<grid, BLOCK, 0, stream>>>(coords, vals, sigma, wptr,
                                                out, P, pixPerN, blocksPerN, nSeg);
    }
}